// Round 15
// baseline (148.794 us; speedup 1.0000x reference)
//
#include <hip/hip_runtime.h>
#include <hip/hip_bf16.h>
#include <math.h>

// BatchGATConv: N nodes, B=2 batches, DIN=128, H=4 heads, D=64, E edges.
// Dispatch plan (5 dispatches):
//   D0: memset deg
//   D1: hist (int4, 4 edges/thread) || prep WT          [independent]
//   D2: scan (single block): CSR offsets + degree-descending node permutation
//   D3: proj_mfma (625 one-tile blocks) || scatter (313 blocks)
//   D4: agg (wave=node via nperm, width-4 depth-2 pipelined gather)

typedef unsigned short ushort;
typedef __attribute__((ext_vector_type(8))) unsigned short ushort8;
typedef __attribute__((ext_vector_type(8))) short short8v;
typedef __attribute__((ext_vector_type(4))) float f32x4;

constexpr int DIN = 128;
constexpr int B   = 2;
constexpr int H   = 4;
constexpr int D   = 64;
constexpr int HD  = H * D;      // 256
constexpr int BHD = B * HD;     // 512
constexpr int NCOL = 272;       // 256 + 16 (8 el/er cols + 8 zero pad)
constexpr int PREP_ELEMS  = NCOL * DIN;                 // 34816
constexpr int PREP_BLOCKS = (PREP_ELEMS + 255) / 256;   // 136
constexpr int SXS = 72;         // LDS transpose row stride (ushorts)

__device__ __forceinline__ float leaky(float x) { return x >= 0.f ? x : 0.2f * x; }

__device__ __forceinline__ ushort f2bf(float f) {
    return __builtin_bit_cast(ushort, __float2bfloat16(f));
}
__device__ __forceinline__ float bf2f(ushort v) {
    return __uint_as_float(((unsigned int)v) << 16);
}

// ---------------- D1: hist || prep ----------------
__global__ __launch_bounds__(256) void hist_prep_kernel(
    const int* __restrict__ dst, int* __restrict__ deg, int E,
    const float* __restrict__ W, const float* __restrict__ attn_l,
    const float* __restrict__ attn_r, ushort* __restrict__ WT, int histBlocks)
{
    const int t = threadIdx.x;
    const int b = blockIdx.x;
    if (b < histBlocks) {
        int e4 = (b * 256 + t) * 4;
        if (e4 + 3 < E) {
            int4 dd = *(const int4*)(dst + e4);
            atomicAdd(&deg[dd.x], 1); atomicAdd(&deg[dd.y], 1);
            atomicAdd(&deg[dd.z], 1); atomicAdd(&deg[dd.w], 1);
        } else {
            for (int e = e4; e < E; ++e) atomicAdd(&deg[dst[e]], 1);
        }
        return;
    }
    int id = (b - histBlocks) * 256 + t;
    if (id >= PREP_ELEMS) return;
    int c = id >> 7, k = id & 127;
    float v;
    if (c < 256) {
        v = W[k * HD + c];
    } else if (c < 264) {
        int j = c - 256, h = j & 3;
        const float* av = (j < 4 ? attn_l : attn_r) + h * D;
        const float* wp = W + k * HD + h * D;
        float s = 0.f;
        for (int d = 0; d < D; ++d) s = fmaf(wp[d], av[d], s);
        v = s;
    } else {
        v = 0.f;
    }
    WT[c * DIN + k] = f2bf(v);
}

// ---------------- D2: scan + degree-descending node sort ----------------
__global__ __launch_bounds__(256) void scan_kernel(
    const int* __restrict__ deg, int* __restrict__ offs,
    int* __restrict__ cursor, int* __restrict__ nperm, int n)
{
    __shared__ int wcarry[4];
    __shared__ int bbase[64];
    const int t = threadIdx.x;
    const int lane = t & 63;
    const int wid = t >> 6;
    int carry = 0;
    const int nstripes = (n + 1023) >> 10;
    for (int s = 0; s < nstripes; ++s) {
        const int base = (s << 10) + t * 4;
        int4 d = make_int4(0, 0, 0, 0);
        if (base + 3 < n) {
            d = *(const int4*)(deg + base);
        } else {
            if (base     < n) d.x = deg[base];
            if (base + 1 < n) d.y = deg[base + 1];
            if (base + 2 < n) d.z = deg[base + 2];
        }
        const int sum4 = (d.x + d.y) + (d.z + d.w);
        int inc = sum4;
#pragma unroll
        for (int o = 1; o < 64; o <<= 1) {
            int v = __shfl_up(inc, o, 64);
            if (lane >= o) inc += v;
        }
        if (lane == 63) wcarry[wid] = inc;
        __syncthreads();
        int wpre = carry;
#pragma unroll
        for (int k = 0; k < 4; ++k) if (k < wid) wpre += wcarry[k];
        const int e0 = wpre + inc - sum4;
        int4 ov;
        ov.x = e0; ov.y = e0 + d.x; ov.z = ov.y + d.y; ov.w = ov.z + d.z;
        if (base + 3 < n) {
            *(int4*)(offs + base) = ov;
            *(int4*)(cursor + base) = ov;
        } else {
            if (base     < n) { offs[base]     = ov.x; cursor[base]     = ov.x; }
            if (base + 1 < n) { offs[base + 1] = ov.y; cursor[base + 1] = ov.y; }
            if (base + 2 < n) { offs[base + 2] = ov.z; cursor[base + 2] = ov.z; }
        }
        carry += (wcarry[0] + wcarry[1]) + (wcarry[2] + wcarry[3]);
        __syncthreads();
    }
    if (t == 0) offs[n] = carry;

    // ---- counting sort of node ids by min(deg,63), DESCENDING ----
    if (t < 64) bbase[t] = 0;
    __syncthreads();
    for (int i = t; i < n; i += 256)
        atomicAdd(&bbase[min(deg[i], 63)], 1);
    __syncthreads();
    if (t == 0) {
        int run = 0;
        for (int b = 63; b >= 0; --b) { int c = bbase[b]; bbase[b] = run; run += c; }
    }
    __syncthreads();
    for (int i = t; i < n; i += 256) {
        int pos = atomicAdd(&bbase[min(deg[i], 63)], 1);
        nperm[pos] = i;
    }
}

// ---------------- D3: proj_mfma (one tile per block) || scatter ----------------
__global__ __launch_bounds__(256) void proj_scatter_kernel(
    const float* __restrict__ feat, const ushort* __restrict__ WT,
    ushort* __restrict__ ftb, float* __restrict__ el, float* __restrict__ er,
    const int* __restrict__ dst, const int* __restrict__ src,
    int* __restrict__ cursor, int* __restrict__ esrc, int E,
    int nTiles)
{
    if ((int)blockIdx.x >= nTiles) {
        // ---- scatter part ----
        int e4 = (((int)blockIdx.x - nTiles) * 256 + (int)threadIdx.x) * 4;
        if (e4 + 3 < E) {
            int4 dd = *(const int4*)(dst + e4);
            int4 ss = *(const int4*)(src + e4);
            int p0 = atomicAdd(&cursor[dd.x], 1); esrc[p0] = ss.x;
            int p1 = atomicAdd(&cursor[dd.y], 1); esrc[p1] = ss.y;
            int p2 = atomicAdd(&cursor[dd.z], 1); esrc[p2] = ss.z;
            int p3 = atomicAdd(&cursor[dd.w], 1); esrc[p3] = ss.w;
        } else {
            for (int e = e4; e < E; ++e) {
                int pos = atomicAdd(&cursor[dst[e]], 1);
                esrc[pos] = src[e];
            }
        }
        return;
    }

    // ---- proj part: one 64x272 tile ----
    __shared__ ushort sxp[4][2][16][SXS];
    const int t = threadIdx.x;
    const int w = t >> 6;
    const int lane = t & 63;
    const int lr = lane & 15;
    const int lk = lane >> 4;

    short8v bfrag[4][4];
#pragma unroll
    for (int ct = 0; ct < 4; ++ct) {
        const int col = w * 64 + ct * 16 + lr;
#pragma unroll
        for (int ks = 0; ks < 4; ++ks)
            bfrag[ct][ks] = *(const short8v*)&WT[col * DIN + ks * 32 + lk * 8];
    }
    short8v efrag[4];
#pragma unroll
    for (int ks = 0; ks < 4; ++ks)
        efrag[ks] = *(const short8v*)&WT[(256 + lr) * DIN + ks * 32 + lk * 8];

    const int rrow = lane >> 2;
    const int seg  = lane & 3;
    const int row0 = blockIdx.x * 64;

    auto loadA = [&](int rt, short8v aout[4]) {
        const float* fp = feat + (size_t)(row0 + rt * 16 + lr) * DIN + lk * 8;
#pragma unroll
        for (int ks = 0; ks < 4; ++ks) {
            f32x4 x0 = *(const f32x4*)(fp + ks * 32);
            f32x4 x1 = *(const f32x4*)(fp + ks * 32 + 4);
            short8v v;
            v[0] = (short)f2bf(x0[0]); v[1] = (short)f2bf(x0[1]);
            v[2] = (short)f2bf(x0[2]); v[3] = (short)f2bf(x0[3]);
            v[4] = (short)f2bf(x1[0]); v[5] = (short)f2bf(x1[1]);
            v[6] = (short)f2bf(x1[2]); v[7] = (short)f2bf(x1[3]);
            aout[ks] = v;
        }
    };

    short8v aP[4], aN[4];
    loadA(0, aP);

#pragma unroll
    for (int rt = 0; rt < 4; ++rt) {
        if (rt < 3) loadA(rt + 1, aN);

        f32x4 acc[4] = {{0.f,0.f,0.f,0.f},{0.f,0.f,0.f,0.f},{0.f,0.f,0.f,0.f},{0.f,0.f,0.f,0.f}};
#pragma unroll
        for (int ct = 0; ct < 4; ++ct)
#pragma unroll
            for (int ks = 0; ks < 4; ++ks)
                acc[ct] = __builtin_amdgcn_mfma_f32_16x16x32_bf16(aP[ks], bfrag[ct][ks], acc[ct], 0, 0, 0);

        ushort (* __restrict__ sw)[SXS] = sxp[w][rt & 1];
#pragma unroll
        for (int ct = 0; ct < 4; ++ct)
#pragma unroll
            for (int r = 0; r < 4; ++r)
                sw[lk * 4 + r][ct * 16 + lr] = f2bf(acc[ct][r]);
        __builtin_amdgcn_wave_barrier();
        ushort8 o0 = *(const ushort8*)&sw[rrow][seg * 16];
        ushort8 o1 = *(const ushort8*)&sw[rrow][seg * 16 + 8];
        ushort* gp = ftb + (size_t)(row0 + rt * 16 + rrow) * HD + w * 64 + seg * 16;
        *(ushort8*)gp = o0;
        *(ushort8*)(gp + 8) = o1;

        if (rt == w) {  // extra tile: el/er columns (wave-uniform branch)
            f32x4 acce = {0.f, 0.f, 0.f, 0.f};
#pragma unroll
            for (int ks = 0; ks < 4; ++ks)
                acce = __builtin_amdgcn_mfma_f32_16x16x32_bf16(aP[ks], efrag[ks], acce, 0, 0, 0);
#pragma unroll
            for (int r = 0; r < 4; ++r) {
                const int row = row0 + rt * 16 + lk * 4 + r;
                if (lr < 4)       el[row * 4 + lr]       = acce[r];
                else if (lr < 8)  er[row * 4 + (lr - 4)] = acce[r];
            }
        }

#pragma unroll
        for (int ks = 0; ks < 4; ++ks) aP[ks] = aN[ks];
    }
}

// ---------------- D4: agg (deg-sorted schedule, pipelined gather) ----------------
// One wave per dst node (via nperm, degree-descending); lane covers cols
// 8*lane..8*lane+7. Width-4 depth-2 pipeline hides the gather latency chain.
__global__ __launch_bounds__(256) void agg_kernel(
    const ushort* __restrict__ ftb, const float* __restrict__ el,
    const float* __restrict__ er, const int* __restrict__ offs,
    const int* __restrict__ esrc, const int* __restrict__ nperm,
    float* __restrict__ out, int N)
{
    const int t = threadIdx.x;
    const int slot = blockIdx.x * 4 + (t >> 6);
    if (slot >= N) return;
    const int n = nperm[slot];
    const int lane = t & 63;
    const int bh = lane >> 3;
    const int beg = offs[n];
    const int end = offs[n + 1];

    const float erd = er[n * 8 + bh];
    const ushort8* __restrict__ ftv = (const ushort8*)ftb;

    float acc[8];
#pragma unroll
    for (int j = 0; j < 8; ++j) acc[j] = 0.f;
    float dsum = 0.f;

    int i = beg;
    if (end - beg >= 8) {
        int sA[4]; ushort8 vA[4]; float xA[4];
#pragma unroll
        for (int u = 0; u < 4; ++u) sA[u] = esrc[i + u];
#pragma unroll
        for (int u = 0; u < 4; ++u) vA[u] = ftv[(unsigned)sA[u] * 64 + lane];
#pragma unroll
        for (int u = 0; u < 4; ++u) xA[u] = el[sA[u] * 8 + bh];

        for (; i + 7 < end; i += 4) {
            int sB[4]; ushort8 vB[4]; float xB[4];
#pragma unroll
            for (int u = 0; u < 4; ++u) sB[u] = esrc[i + 4 + u];
#pragma unroll
            for (int u = 0; u < 4; ++u) vB[u] = ftv[(unsigned)sB[u] * 64 + lane];
#pragma unroll
            for (int u = 0; u < 4; ++u) xB[u] = el[sB[u] * 8 + bh];

            float w[4];
#pragma unroll
            for (int u = 0; u < 4; ++u) { w[u] = __expf(leaky(xA[u] + erd)); }
            dsum += (w[0] + w[1]) + (w[2] + w[3]);
#pragma unroll
            for (int j = 0; j < 8; ++j) {
                float a = acc[j];
#pragma unroll
                for (int u = 0; u < 4; ++u) a = fmaf(w[u], bf2f(vA[u][j]), a);
                acc[j] = a;
            }
#pragma unroll
            for (int u = 0; u < 4; ++u) { sA[u] = sB[u]; vA[u] = vB[u]; xA[u] = xB[u]; }
        }
        float w[4];
#pragma unroll
        for (int u = 0; u < 4; ++u) { w[u] = __expf(leaky(xA[u] + erd)); }
        dsum += (w[0] + w[1]) + (w[2] + w[3]);
#pragma unroll
        for (int j = 0; j < 8; ++j) {
            float a = acc[j];
#pragma unroll
            for (int u = 0; u < 4; ++u) a = fmaf(w[u], bf2f(vA[u][j]), a);
            acc[j] = a;
        }
        i += 4;
    }
    for (; i < end; ++i) {
        int s0 = esrc[i];
        ushort8 v0 = ftv[(unsigned)s0 * 64 + lane];
        float w0 = __expf(leaky(el[s0 * 8 + bh] + erd));
        dsum += w0;
#pragma unroll
        for (int j = 0; j < 8; ++j) acc[j] = fmaf(w0, bf2f(v0[j]), acc[j]);
    }

    const float sc = (end > beg) ? (1.f / dsum) : 0.f;
    float4 o0, o1;
    o0.x = leaky(acc[0] * sc); o0.y = leaky(acc[1] * sc);
    o0.z = leaky(acc[2] * sc); o0.w = leaky(acc[3] * sc);
    o1.x = leaky(acc[4] * sc); o1.y = leaky(acc[5] * sc);
    o1.z = leaky(acc[6] * sc); o1.w = leaky(acc[7] * sc);
    float* op = out + (size_t)n * BHD + lane * 8;
    *(float4*)op = o0;
    *(float4*)(op + 4) = o1;
}

extern "C" void kernel_launch(void* const* d_in, const int* in_sizes, int n_in,
                              void* d_out, int out_size, void* d_ws, size_t ws_size,
                              hipStream_t stream)
{
    const float* feat   = (const float*)d_in[0];
    const float* W      = (const float*)d_in[1];
    const float* attn_l = (const float*)d_in[2];
    const float* attn_r = (const float*)d_in[3];
    const int*   src    = (const int*)d_in[4];
    const int*   dst    = (const int*)d_in[5];
    float* out = (float*)d_out;

    const int N = in_sizes[0] / (B * DIN);
    const int E = in_sizes[4];
    const int R = N * B;
    const int nTiles = R / 64;                    // 625 for R=40000 (R % 64 == 0)
    const int histBlocks = (E / 4 + 255) / 256;
    const int edgeBlocks = histBlocks;

    auto align_up = [](size_t x) { return (x + 255) & ~(size_t)255; };
    size_t off = 0;
    char* base = (char*)d_ws;
    ushort* ftb = (ushort*)(base + off); off += align_up((size_t)R * HD * sizeof(ushort));
    float* el   = (float*)(base + off); off += align_up((size_t)R * H * sizeof(float));
    float* er   = (float*)(base + off); off += align_up((size_t)R * H * sizeof(float));
    ushort* WT  = (ushort*)(base + off); off += align_up((size_t)NCOL * DIN * sizeof(ushort));
    int* deg    = (int*)(base + off); off += align_up((size_t)N * sizeof(int));
    int* offs   = (int*)(base + off); off += align_up((size_t)(N + 1) * sizeof(int));
    int* cursor = (int*)(base + off); off += align_up((size_t)N * sizeof(int));
    int* nperm  = (int*)(base + off); off += align_up((size_t)N * sizeof(int));
    int* esrc   = (int*)(base + off); off += align_up((size_t)E * sizeof(int));
    (void)ws_size; (void)n_in; (void)out_size;

    hipMemsetAsync(deg, 0, (size_t)N * sizeof(int), stream);

    hist_prep_kernel<<<histBlocks + PREP_BLOCKS, 256, 0, stream>>>(
        dst, deg, E, W, attn_l, attn_r, WT, histBlocks);
    scan_kernel<<<1, 256, 0, stream>>>(deg, offs, cursor, nperm, N);
    proj_scatter_kernel<<<nTiles + edgeBlocks, 256, 0, stream>>>(
        feat, WT, ftb, el, er, dst, src, cursor, esrc, E, nTiles);
    agg_kernel<<<(N + 3) / 4, 256, 0, stream>>>(ftb, el, er, offs, esrc, nperm, out, N);
}

// Round 16
// 122.252 us; speedup vs baseline: 1.2171x; 1.2171x over previous
//
#include <hip/hip_runtime.h>
#include <hip/hip_bf16.h>
#include <math.h>

// BatchGATConv: N nodes, B=2 batches, DIN=128, H=4 heads, D=64, E edges.
// Dispatch plan (5 dispatches, scatter hidden under proj):
//   D0: memset deg
//   D1: hist (int4, 4 edges/thread) || prep WT          [independent]
//   D2: scan (single small block; needs only hist)
//   D3: proj_mfma || scatter (block-range split; scatter needs only scan)
//   D4: agg (wave=node, readfirstlane-uniform n -> scalar esrc/offs loads,
//       width-4 depth-2 software-pipelined gather)

typedef unsigned short ushort;
typedef __attribute__((ext_vector_type(8))) unsigned short ushort8;
typedef __attribute__((ext_vector_type(8))) short short8v;
typedef __attribute__((ext_vector_type(4))) float f32x4;

constexpr int DIN = 128;
constexpr int B   = 2;
constexpr int H   = 4;
constexpr int D   = 64;
constexpr int HD  = H * D;      // 256
constexpr int BHD = B * HD;     // 512
constexpr int NCOL = 272;       // 256 + 16 (8 el/er cols + 8 zero pad)
constexpr int PREP_ELEMS  = NCOL * DIN;                 // 34816
constexpr int PREP_BLOCKS = (PREP_ELEMS + 255) / 256;   // 136
constexpr int SXS = 72;         // LDS transpose row stride (ushorts)

__device__ __forceinline__ float leaky(float x) { return x >= 0.f ? x : 0.2f * x; }

__device__ __forceinline__ ushort f2bf(float f) {
    return __builtin_bit_cast(ushort, __float2bfloat16(f));
}
__device__ __forceinline__ float bf2f(ushort v) {
    return __uint_as_float(((unsigned int)v) << 16);
}

// ---------------- D1: hist || prep ----------------
__global__ __launch_bounds__(256) void hist_prep_kernel(
    const int* __restrict__ dst, int* __restrict__ deg, int E,
    const float* __restrict__ W, const float* __restrict__ attn_l,
    const float* __restrict__ attn_r, ushort* __restrict__ WT, int histBlocks)
{
    const int t = threadIdx.x;
    const int b = blockIdx.x;
    if (b < histBlocks) {
        int e4 = (b * 256 + t) * 4;
        if (e4 + 3 < E) {
            int4 dd = *(const int4*)(dst + e4);
            atomicAdd(&deg[dd.x], 1); atomicAdd(&deg[dd.y], 1);
            atomicAdd(&deg[dd.z], 1); atomicAdd(&deg[dd.w], 1);
        } else {
            for (int e = e4; e < E; ++e) atomicAdd(&deg[dst[e]], 1);
        }
        return;
    }
    int id = (b - histBlocks) * 256 + t;
    if (id >= PREP_ELEMS) return;
    int c = id >> 7, k = id & 127;
    float v;
    if (c < 256) {
        v = W[k * HD + c];
    } else if (c < 264) {
        int j = c - 256, h = j & 3;
        const float* av = (j < 4 ? attn_l : attn_r) + h * D;
        const float* wp = W + k * HD + h * D;
        float s = 0.f;
        for (int d = 0; d < D; ++d) s = fmaf(wp[d], av[d], s);
        v = s;
    } else {
        v = 0.f;
    }
    WT[c * DIN + k] = f2bf(v);
}

// ---------------- D2: striped coalesced single-block scan ----------------
__global__ __launch_bounds__(256) void scan_kernel(
    const int* __restrict__ deg, int* __restrict__ offs,
    int* __restrict__ cursor, int n)
{
    __shared__ int wcarry[4];
    const int t = threadIdx.x;
    const int lane = t & 63;
    const int wid = t >> 6;
    int carry = 0;
    const int nstripes = (n + 1023) >> 10;
    for (int s = 0; s < nstripes; ++s) {
        const int base = (s << 10) + t * 4;
        int4 d = make_int4(0, 0, 0, 0);
        if (base + 3 < n) {
            d = *(const int4*)(deg + base);
        } else {
            if (base     < n) d.x = deg[base];
            if (base + 1 < n) d.y = deg[base + 1];
            if (base + 2 < n) d.z = deg[base + 2];
        }
        const int sum4 = (d.x + d.y) + (d.z + d.w);
        int inc = sum4;
#pragma unroll
        for (int o = 1; o < 64; o <<= 1) {
            int v = __shfl_up(inc, o, 64);
            if (lane >= o) inc += v;
        }
        if (lane == 63) wcarry[wid] = inc;
        __syncthreads();
        int wpre = carry;
#pragma unroll
        for (int k = 0; k < 4; ++k) if (k < wid) wpre += wcarry[k];
        const int e0 = wpre + inc - sum4;
        int4 ov;
        ov.x = e0; ov.y = e0 + d.x; ov.z = ov.y + d.y; ov.w = ov.z + d.z;
        if (base + 3 < n) {
            *(int4*)(offs + base) = ov;
            *(int4*)(cursor + base) = ov;
        } else {
            if (base     < n) { offs[base]     = ov.x; cursor[base]     = ov.x; }
            if (base + 1 < n) { offs[base + 1] = ov.y; cursor[base + 1] = ov.y; }
            if (base + 2 < n) { offs[base + 2] = ov.z; cursor[base + 2] = ov.z; }
        }
        carry += (wcarry[0] + wcarry[1]) + (wcarry[2] + wcarry[3]);
        __syncthreads();
    }
    if (t == 0) offs[n] = carry;
}

// ---------------- D3: proj_mfma || scatter ----------------
__global__ __launch_bounds__(256) void proj_scatter_kernel(
    const float* __restrict__ feat, const ushort* __restrict__ WT,
    ushort* __restrict__ ftb, float* __restrict__ el, float* __restrict__ er,
    const int* __restrict__ dst, const int* __restrict__ src,
    int* __restrict__ cursor, int* __restrict__ esrc, int E,
    int nTiles)
{
    if ((int)blockIdx.x >= nTiles) {
        // ---- scatter part ----
        int e4 = (((int)blockIdx.x - nTiles) * 256 + (int)threadIdx.x) * 4;
        if (e4 + 3 < E) {
            int4 dd = *(const int4*)(dst + e4);
            int4 ss = *(const int4*)(src + e4);
            int p0 = atomicAdd(&cursor[dd.x], 1); esrc[p0] = ss.x;
            int p1 = atomicAdd(&cursor[dd.y], 1); esrc[p1] = ss.y;
            int p2 = atomicAdd(&cursor[dd.z], 1); esrc[p2] = ss.z;
            int p3 = atomicAdd(&cursor[dd.w], 1); esrc[p3] = ss.w;
        } else {
            for (int e = e4; e < E; ++e) {
                int pos = atomicAdd(&cursor[dst[e]], 1);
                esrc[pos] = src[e];
            }
        }
        return;
    }

    // ---- proj part: one 64x272 tile ----
    __shared__ ushort sxp[4][2][16][SXS];
    const int t = threadIdx.x;
    const int w = t >> 6;
    const int lane = t & 63;
    const int lr = lane & 15;
    const int lk = lane >> 4;

    short8v bfrag[4][4];
#pragma unroll
    for (int ct = 0; ct < 4; ++ct) {
        const int col = w * 64 + ct * 16 + lr;
#pragma unroll
        for (int ks = 0; ks < 4; ++ks)
            bfrag[ct][ks] = *(const short8v*)&WT[col * DIN + ks * 32 + lk * 8];
    }
    short8v efrag[4];
#pragma unroll
    for (int ks = 0; ks < 4; ++ks)
        efrag[ks] = *(const short8v*)&WT[(256 + lr) * DIN + ks * 32 + lk * 8];

    const int rrow = lane >> 2;
    const int seg  = lane & 3;
    const int row0 = blockIdx.x * 64;

    auto loadA = [&](int rt, short8v aout[4]) {
        const float* fp = feat + (size_t)(row0 + rt * 16 + lr) * DIN + lk * 8;
#pragma unroll
        for (int ks = 0; ks < 4; ++ks) {
            f32x4 x0 = *(const f32x4*)(fp + ks * 32);
            f32x4 x1 = *(const f32x4*)(fp + ks * 32 + 4);
            short8v v;
            v[0] = (short)f2bf(x0[0]); v[1] = (short)f2bf(x0[1]);
            v[2] = (short)f2bf(x0[2]); v[3] = (short)f2bf(x0[3]);
            v[4] = (short)f2bf(x1[0]); v[5] = (short)f2bf(x1[1]);
            v[6] = (short)f2bf(x1[2]); v[7] = (short)f2bf(x1[3]);
            aout[ks] = v;
        }
    };

    short8v aP[4], aN[4];
    loadA(0, aP);

#pragma unroll
    for (int rt = 0; rt < 4; ++rt) {
        if (rt < 3) loadA(rt + 1, aN);

        f32x4 acc[4] = {{0.f,0.f,0.f,0.f},{0.f,0.f,0.f,0.f},{0.f,0.f,0.f,0.f},{0.f,0.f,0.f,0.f}};
#pragma unroll
        for (int ct = 0; ct < 4; ++ct)
#pragma unroll
            for (int ks = 0; ks < 4; ++ks)
                acc[ct] = __builtin_amdgcn_mfma_f32_16x16x32_bf16(aP[ks], bfrag[ct][ks], acc[ct], 0, 0, 0);

        ushort (* __restrict__ sw)[SXS] = sxp[w][rt & 1];
#pragma unroll
        for (int ct = 0; ct < 4; ++ct)
#pragma unroll
            for (int r = 0; r < 4; ++r)
                sw[lk * 4 + r][ct * 16 + lr] = f2bf(acc[ct][r]);
        __builtin_amdgcn_wave_barrier();
        ushort8 o0 = *(const ushort8*)&sw[rrow][seg * 16];
        ushort8 o1 = *(const ushort8*)&sw[rrow][seg * 16 + 8];
        ushort* gp = ftb + (size_t)(row0 + rt * 16 + rrow) * HD + w * 64 + seg * 16;
        *(ushort8*)gp = o0;
        *(ushort8*)(gp + 8) = o1;

        if (rt == w) {  // extra tile: el/er columns (wave-uniform branch)
            f32x4 acce = {0.f, 0.f, 0.f, 0.f};
#pragma unroll
            for (int ks = 0; ks < 4; ++ks)
                acce = __builtin_amdgcn_mfma_f32_16x16x32_bf16(aP[ks], efrag[ks], acce, 0, 0, 0);
#pragma unroll
            for (int r = 0; r < 4; ++r) {
                const int row = row0 + rt * 16 + lk * 4 + r;
                if (lr < 4)       el[row * 4 + lr]       = acce[r];
                else if (lr < 8)  er[row * 4 + (lr - 4)] = acce[r];
            }
        }

#pragma unroll
        for (int ks = 0; ks < 4; ++ks) aP[ks] = aN[ks];
    }
}

// ---------------- D4: agg (uniform-n scalar loads + pipelined gather) ----------------
// One wave per dst node; n forced wave-uniform via readfirstlane so offs/esrc
// become scalar (s_load) traffic, freeing the vector-memory pipe for ftv gathers.
// Width-4 depth-2 pipeline hides the esrc->ftv dependent latency chain.
__global__ __launch_bounds__(256) void agg_kernel(
    const ushort* __restrict__ ftb, const float* __restrict__ el,
    const float* __restrict__ er, const int* __restrict__ offs,
    const int* __restrict__ esrc, float* __restrict__ out, int N)
{
    const int t = threadIdx.x;
    const int n = __builtin_amdgcn_readfirstlane(blockIdx.x * 4 + (t >> 6));
    if (n >= N) return;
    const int lane = t & 63;
    const int bh = lane >> 3;
    const int beg = __builtin_amdgcn_readfirstlane(offs[n]);
    const int end = __builtin_amdgcn_readfirstlane(offs[n + 1]);

    const float erd = er[n * 8 + bh];
    const ushort8* __restrict__ ftv = (const ushort8*)ftb;

    float acc[8];
#pragma unroll
    for (int j = 0; j < 8; ++j) acc[j] = 0.f;
    float dsum = 0.f;

    int i = beg;
    if (end - beg >= 8) {
        int sA[4]; ushort8 vA[4]; float xA[4];
#pragma unroll
        for (int u = 0; u < 4; ++u) sA[u] = __builtin_amdgcn_readfirstlane(esrc[i + u]);
#pragma unroll
        for (int u = 0; u < 4; ++u) vA[u] = ftv[(unsigned)sA[u] * 64 + lane];
#pragma unroll
        for (int u = 0; u < 4; ++u) xA[u] = el[sA[u] * 8 + bh];

        for (; i + 7 < end; i += 4) {
            int sB[4]; ushort8 vB[4]; float xB[4];
#pragma unroll
            for (int u = 0; u < 4; ++u) sB[u] = __builtin_amdgcn_readfirstlane(esrc[i + 4 + u]);
#pragma unroll
            for (int u = 0; u < 4; ++u) vB[u] = ftv[(unsigned)sB[u] * 64 + lane];
#pragma unroll
            for (int u = 0; u < 4; ++u) xB[u] = el[sB[u] * 8 + bh];

            float w[4];
#pragma unroll
            for (int u = 0; u < 4; ++u) { w[u] = __expf(leaky(xA[u] + erd)); }
            dsum += (w[0] + w[1]) + (w[2] + w[3]);
#pragma unroll
            for (int j = 0; j < 8; ++j) {
                float a = acc[j];
#pragma unroll
                for (int u = 0; u < 4; ++u) a = fmaf(w[u], bf2f(vA[u][j]), a);
                acc[j] = a;
            }
#pragma unroll
            for (int u = 0; u < 4; ++u) { sA[u] = sB[u]; vA[u] = vB[u]; xA[u] = xB[u]; }
        }
        float w[4];
#pragma unroll
        for (int u = 0; u < 4; ++u) { w[u] = __expf(leaky(xA[u] + erd)); }
        dsum += (w[0] + w[1]) + (w[2] + w[3]);
#pragma unroll
        for (int j = 0; j < 8; ++j) {
            float a = acc[j];
#pragma unroll
            for (int u = 0; u < 4; ++u) a = fmaf(w[u], bf2f(vA[u][j]), a);
            acc[j] = a;
        }
        i += 4;
    }
    for (; i < end; ++i) {
        int s0 = __builtin_amdgcn_readfirstlane(esrc[i]);
        ushort8 v0 = ftv[(unsigned)s0 * 64 + lane];
        float w0 = __expf(leaky(el[s0 * 8 + bh] + erd));
        dsum += w0;
#pragma unroll
        for (int j = 0; j < 8; ++j) acc[j] = fmaf(w0, bf2f(v0[j]), acc[j]);
    }

    const float sc = (end > beg) ? (1.f / dsum) : 0.f;
    float4 o0, o1;
    o0.x = leaky(acc[0] * sc); o0.y = leaky(acc[1] * sc);
    o0.z = leaky(acc[2] * sc); o0.w = leaky(acc[3] * sc);
    o1.x = leaky(acc[4] * sc); o1.y = leaky(acc[5] * sc);
    o1.z = leaky(acc[6] * sc); o1.w = leaky(acc[7] * sc);
    float* op = out + (size_t)n * BHD + lane * 8;
    *(float4*)op = o0;
    *(float4*)(op + 4) = o1;
}

extern "C" void kernel_launch(void* const* d_in, const int* in_sizes, int n_in,
                              void* d_out, int out_size, void* d_ws, size_t ws_size,
                              hipStream_t stream)
{
    const float* feat   = (const float*)d_in[0];
    const float* W      = (const float*)d_in[1];
    const float* attn_l = (const float*)d_in[2];
    const float* attn_r = (const float*)d_in[3];
    const int*   src    = (const int*)d_in[4];
    const int*   dst    = (const int*)d_in[5];
    float* out = (float*)d_out;

    const int N = in_sizes[0] / (B * DIN);
    const int E = in_sizes[4];
    const int R = N * B;
    const int nTiles = R / 64;                    // 625 for R=40000 (R % 64 == 0)
    const int histBlocks = (E / 4 + 255) / 256;
    const int edgeBlocks = histBlocks;

    auto align_up = [](size_t x) { return (x + 255) & ~(size_t)255; };
    size_t off = 0;
    char* base = (char*)d_ws;
    ushort* ftb = (ushort*)(base + off); off += align_up((size_t)R * HD * sizeof(ushort));
    float* el   = (float*)(base + off); off += align_up((size_t)R * H * sizeof(float));
    float* er   = (float*)(base + off); off += align_up((size_t)R * H * sizeof(float));
    ushort* WT  = (ushort*)(base + off); off += align_up((size_t)NCOL * DIN * sizeof(ushort));
    int* deg    = (int*)(base + off); off += align_up((size_t)N * sizeof(int));
    int* offs   = (int*)(base + off); off += align_up((size_t)(N + 1) * sizeof(int));
    int* cursor = (int*)(base + off); off += align_up((size_t)N * sizeof(int));
    int* esrc   = (int*)(base + off); off += align_up((size_t)E * sizeof(int));
    (void)ws_size; (void)n_in; (void)out_size;

    hipMemsetAsync(deg, 0, (size_t)N * sizeof(int), stream);

    hist_prep_kernel<<<histBlocks + PREP_BLOCKS, 256, 0, stream>>>(
        dst, deg, E, W, attn_l, attn_r, WT, histBlocks);
    scan_kernel<<<1, 256, 0, stream>>>(deg, offs, cursor, N);
    proj_scatter_kernel<<<nTiles + edgeBlocks, 256, 0, stream>>>(
        feat, WT, ftb, el, er, dst, src, cursor, esrc, E, nTiles);
    agg_kernel<<<(N + 3) / 4, 256, 0, stream>>>(ftb, el, er, offs, esrc, out, N);
}

// Round 17
// 120.875 us; speedup vs baseline: 1.2310x; 1.0114x over previous
//
#include <hip/hip_runtime.h>
#include <hip/hip_bf16.h>
#include <math.h>

// BatchGATConv: N nodes, B=2 batches, DIN=128, H=4 heads, D=64, E edges.
// Dispatch plan (5 dispatches):
//   D0: memset deg
//   D1: hist (int4) || prep WT || featcvt (feat f32 -> bf16)   [all independent]
//   D2: scan (single block; needs only hist)
//   D3: proj_mfma (bf16 A-loads, no inline cvt) || scatter
//   D4: agg (R14 form: wave=node, width-4 depth-2 pipelined gather) -- at its
//       measured structural floor (~50us, 147MB per-XCD cold misses @ ~3.8TB/s)

typedef unsigned short ushort;
typedef __attribute__((ext_vector_type(8))) unsigned short ushort8;
typedef __attribute__((ext_vector_type(8))) short short8v;
typedef __attribute__((ext_vector_type(4))) float f32x4;

constexpr int DIN = 128;
constexpr int B   = 2;
constexpr int H   = 4;
constexpr int D   = 64;
constexpr int HD  = H * D;      // 256
constexpr int BHD = B * HD;     // 512
constexpr int NCOL = 272;       // 256 + 16 (8 el/er cols + 8 zero pad)
constexpr int PREP_ELEMS  = NCOL * DIN;                 // 34816
constexpr int PREP_BLOCKS = (PREP_ELEMS + 255) / 256;   // 136
constexpr int SXS = 72;         // LDS transpose row stride (ushorts)

__device__ __forceinline__ float leaky(float x) { return x >= 0.f ? x : 0.2f * x; }

__device__ __forceinline__ ushort f2bf(float f) {
    return __builtin_bit_cast(ushort, __float2bfloat16(f));
}
__device__ __forceinline__ float bf2f(ushort v) {
    return __uint_as_float(((unsigned int)v) << 16);
}

// ---------------- D1: hist || prep || featcvt ----------------
__global__ __launch_bounds__(256) void hist_prep_cvt_kernel(
    const int* __restrict__ dst, int* __restrict__ deg, int E,
    const float* __restrict__ W, const float* __restrict__ attn_l,
    const float* __restrict__ attn_r, ushort* __restrict__ WT,
    const float* __restrict__ feat, ushort* __restrict__ featb, int R,
    int histBlocks)
{
    const int t = threadIdx.x;
    const int b = blockIdx.x;
    if (b < histBlocks) {
        int e4 = (b * 256 + t) * 4;
        if (e4 + 3 < E) {
            int4 dd = *(const int4*)(dst + e4);
            atomicAdd(&deg[dd.x], 1); atomicAdd(&deg[dd.y], 1);
            atomicAdd(&deg[dd.z], 1); atomicAdd(&deg[dd.w], 1);
        } else {
            for (int e = e4; e < E; ++e) atomicAdd(&deg[dst[e]], 1);
        }
        return;
    }
    if (b < histBlocks + PREP_BLOCKS) {
        int id = (b - histBlocks) * 256 + t;
        if (id >= PREP_ELEMS) return;
        int c = id >> 7, k = id & 127;
        float v;
        if (c < 256) {
            v = W[k * HD + c];
        } else if (c < 264) {
            int j = c - 256, h = j & 3;
            const float* av = (j < 4 ? attn_l : attn_r) + h * D;
            const float* wp = W + k * HD + h * D;
            float s = 0.f;
            for (int d = 0; d < D; ++d) s = fmaf(wp[d], av[d], s);
            v = s;
        } else {
            v = 0.f;
        }
        WT[c * DIN + k] = f2bf(v);
        return;
    }
    // ---- featcvt: 8 floats -> 8 bf16 per thread ----
    size_t g8 = ((size_t)(b - histBlocks - PREP_BLOCKS) * 256 + t) * 8;
    if (g8 + 7 < (size_t)R * DIN) {
        f32x4 x0 = *(const f32x4*)(feat + g8);
        f32x4 x1 = *(const f32x4*)(feat + g8 + 4);
        ushort8 v;
        v[0] = f2bf(x0[0]); v[1] = f2bf(x0[1]); v[2] = f2bf(x0[2]); v[3] = f2bf(x0[3]);
        v[4] = f2bf(x1[0]); v[5] = f2bf(x1[1]); v[6] = f2bf(x1[2]); v[7] = f2bf(x1[3]);
        *(ushort8*)(featb + g8) = v;
    }
}

// ---------------- D2: striped coalesced single-block scan ----------------
__global__ __launch_bounds__(256) void scan_kernel(
    const int* __restrict__ deg, int* __restrict__ offs,
    int* __restrict__ cursor, int n)
{
    __shared__ int wcarry[4];
    const int t = threadIdx.x;
    const int lane = t & 63;
    const int wid = t >> 6;
    int carry = 0;
    const int nstripes = (n + 1023) >> 10;
    for (int s = 0; s < nstripes; ++s) {
        const int base = (s << 10) + t * 4;
        int4 d = make_int4(0, 0, 0, 0);
        if (base + 3 < n) {
            d = *(const int4*)(deg + base);
        } else {
            if (base     < n) d.x = deg[base];
            if (base + 1 < n) d.y = deg[base + 1];
            if (base + 2 < n) d.z = deg[base + 2];
        }
        const int sum4 = (d.x + d.y) + (d.z + d.w);
        int inc = sum4;
#pragma unroll
        for (int o = 1; o < 64; o <<= 1) {
            int v = __shfl_up(inc, o, 64);
            if (lane >= o) inc += v;
        }
        if (lane == 63) wcarry[wid] = inc;
        __syncthreads();
        int wpre = carry;
#pragma unroll
        for (int k = 0; k < 4; ++k) if (k < wid) wpre += wcarry[k];
        const int e0 = wpre + inc - sum4;
        int4 ov;
        ov.x = e0; ov.y = e0 + d.x; ov.z = ov.y + d.y; ov.w = ov.z + d.z;
        if (base + 3 < n) {
            *(int4*)(offs + base) = ov;
            *(int4*)(cursor + base) = ov;
        } else {
            if (base     < n) { offs[base]     = ov.x; cursor[base]     = ov.x; }
            if (base + 1 < n) { offs[base + 1] = ov.y; cursor[base + 1] = ov.y; }
            if (base + 2 < n) { offs[base + 2] = ov.z; cursor[base + 2] = ov.z; }
        }
        carry += (wcarry[0] + wcarry[1]) + (wcarry[2] + wcarry[3]);
        __syncthreads();
    }
    if (t == 0) offs[n] = carry;
}

// ---------------- D3: proj_mfma (bf16 A) || scatter ----------------
__global__ __launch_bounds__(256) void proj_scatter_kernel(
    const ushort* __restrict__ featb, const ushort* __restrict__ WT,
    ushort* __restrict__ ftb, float* __restrict__ el, float* __restrict__ er,
    const int* __restrict__ dst, const int* __restrict__ src,
    int* __restrict__ cursor, int* __restrict__ esrc, int E,
    int nTiles)
{
    if ((int)blockIdx.x >= nTiles) {
        // ---- scatter part ----
        int e4 = (((int)blockIdx.x - nTiles) * 256 + (int)threadIdx.x) * 4;
        if (e4 + 3 < E) {
            int4 dd = *(const int4*)(dst + e4);
            int4 ss = *(const int4*)(src + e4);
            int p0 = atomicAdd(&cursor[dd.x], 1); esrc[p0] = ss.x;
            int p1 = atomicAdd(&cursor[dd.y], 1); esrc[p1] = ss.y;
            int p2 = atomicAdd(&cursor[dd.z], 1); esrc[p2] = ss.z;
            int p3 = atomicAdd(&cursor[dd.w], 1); esrc[p3] = ss.w;
        } else {
            for (int e = e4; e < E; ++e) {
                int pos = atomicAdd(&cursor[dst[e]], 1);
                esrc[pos] = src[e];
            }
        }
        return;
    }

    // ---- proj part: one 64x272 tile, A-frags loaded directly as bf16 ----
    __shared__ ushort sxp[4][2][16][SXS];
    const int t = threadIdx.x;
    const int w = t >> 6;
    const int lane = t & 63;
    const int lr = lane & 15;
    const int lk = lane >> 4;

    short8v bfrag[4][4];
#pragma unroll
    for (int ct = 0; ct < 4; ++ct) {
        const int col = w * 64 + ct * 16 + lr;
#pragma unroll
        for (int ks = 0; ks < 4; ++ks)
            bfrag[ct][ks] = *(const short8v*)&WT[col * DIN + ks * 32 + lk * 8];
    }
    short8v efrag[4];
#pragma unroll
    for (int ks = 0; ks < 4; ++ks)
        efrag[ks] = *(const short8v*)&WT[(256 + lr) * DIN + ks * 32 + lk * 8];

    const int rrow = lane >> 2;
    const int seg  = lane & 3;
    const int row0 = blockIdx.x * 64;

    auto loadA = [&](int rt, short8v aout[4]) {
        const ushort* fp = featb + (size_t)(row0 + rt * 16 + lr) * DIN + lk * 8;
#pragma unroll
        for (int ks = 0; ks < 4; ++ks)
            aout[ks] = *(const short8v*)(fp + ks * 32);
    };

    short8v aP[4], aN[4];
    loadA(0, aP);

#pragma unroll
    for (int rt = 0; rt < 4; ++rt) {
        if (rt < 3) loadA(rt + 1, aN);

        f32x4 acc[4] = {{0.f,0.f,0.f,0.f},{0.f,0.f,0.f,0.f},{0.f,0.f,0.f,0.f},{0.f,0.f,0.f,0.f}};
#pragma unroll
        for (int ct = 0; ct < 4; ++ct)
#pragma unroll
            for (int ks = 0; ks < 4; ++ks)
                acc[ct] = __builtin_amdgcn_mfma_f32_16x16x32_bf16(aP[ks], bfrag[ct][ks], acc[ct], 0, 0, 0);

        ushort (* __restrict__ sw)[SXS] = sxp[w][rt & 1];
#pragma unroll
        for (int ct = 0; ct < 4; ++ct)
#pragma unroll
            for (int r = 0; r < 4; ++r)
                sw[lk * 4 + r][ct * 16 + lr] = f2bf(acc[ct][r]);
        __builtin_amdgcn_wave_barrier();
        ushort8 o0 = *(const ushort8*)&sw[rrow][seg * 16];
        ushort8 o1 = *(const ushort8*)&sw[rrow][seg * 16 + 8];
        ushort* gp = ftb + (size_t)(row0 + rt * 16 + rrow) * HD + w * 64 + seg * 16;
        *(ushort8*)gp = o0;
        *(ushort8*)(gp + 8) = o1;

        if (rt == w) {  // extra tile: el/er columns (wave-uniform branch)
            f32x4 acce = {0.f, 0.f, 0.f, 0.f};
#pragma unroll
            for (int ks = 0; ks < 4; ++ks)
                acce = __builtin_amdgcn_mfma_f32_16x16x32_bf16(aP[ks], efrag[ks], acce, 0, 0, 0);
#pragma unroll
            for (int r = 0; r < 4; ++r) {
                const int row = row0 + rt * 16 + lk * 4 + r;
                if (lr < 4)       el[row * 4 + lr]       = acce[r];
                else if (lr < 8)  er[row * 4 + (lr - 4)] = acce[r];
            }
        }

#pragma unroll
        for (int ks = 0; ks < 4; ++ks) aP[ks] = aN[ks];
    }
}

// ---------------- D4: agg (R14 form, at structural floor) ----------------
__global__ __launch_bounds__(256) void agg_kernel(
    const ushort* __restrict__ ftb, const float* __restrict__ el,
    const float* __restrict__ er, const int* __restrict__ offs,
    const int* __restrict__ esrc, float* __restrict__ out, int N)
{
    const int t = threadIdx.x;
    const int n = blockIdx.x * 4 + (t >> 6);
    if (n >= N) return;
    const int lane = t & 63;
    const int bh = lane >> 3;
    const int beg = offs[n];
    const int end = offs[n + 1];

    const float erd = er[n * 8 + bh];
    const ushort8* __restrict__ ftv = (const ushort8*)ftb;

    float acc[8];
#pragma unroll
    for (int j = 0; j < 8; ++j) acc[j] = 0.f;
    float dsum = 0.f;

    int i = beg;
    if (end - beg >= 8) {
        int sA[4]; ushort8 vA[4]; float xA[4];
#pragma unroll
        for (int u = 0; u < 4; ++u) sA[u] = esrc[i + u];
#pragma unroll
        for (int u = 0; u < 4; ++u) vA[u] = ftv[(unsigned)sA[u] * 64 + lane];
#pragma unroll
        for (int u = 0; u < 4; ++u) xA[u] = el[sA[u] * 8 + bh];

        for (; i + 7 < end; i += 4) {
            int sB[4]; ushort8 vB[4]; float xB[4];
#pragma unroll
            for (int u = 0; u < 4; ++u) sB[u] = esrc[i + 4 + u];
#pragma unroll
            for (int u = 0; u < 4; ++u) vB[u] = ftv[(unsigned)sB[u] * 64 + lane];
#pragma unroll
            for (int u = 0; u < 4; ++u) xB[u] = el[sB[u] * 8 + bh];

            float w[4];
#pragma unroll
            for (int u = 0; u < 4; ++u) { w[u] = __expf(leaky(xA[u] + erd)); }
            dsum += (w[0] + w[1]) + (w[2] + w[3]);
#pragma unroll
            for (int j = 0; j < 8; ++j) {
                float a = acc[j];
#pragma unroll
                for (int u = 0; u < 4; ++u) a = fmaf(w[u], bf2f(vA[u][j]), a);
                acc[j] = a;
            }
#pragma unroll
            for (int u = 0; u < 4; ++u) { sA[u] = sB[u]; vA[u] = vB[u]; xA[u] = xB[u]; }
        }
        float w[4];
#pragma unroll
        for (int u = 0; u < 4; ++u) { w[u] = __expf(leaky(xA[u] + erd)); }
        dsum += (w[0] + w[1]) + (w[2] + w[3]);
#pragma unroll
        for (int j = 0; j < 8; ++j) {
            float a = acc[j];
#pragma unroll
            for (int u = 0; u < 4; ++u) a = fmaf(w[u], bf2f(vA[u][j]), a);
            acc[j] = a;
        }
        i += 4;
    }
    for (; i < end; ++i) {
        int s0 = esrc[i];
        ushort8 v0 = ftv[(unsigned)s0 * 64 + lane];
        float w0 = __expf(leaky(el[s0 * 8 + bh] + erd));
        dsum += w0;
#pragma unroll
        for (int j = 0; j < 8; ++j) acc[j] = fmaf(w0, bf2f(v0[j]), acc[j]);
    }

    const float sc = (end > beg) ? (1.f / dsum) : 0.f;
    float4 o0, o1;
    o0.x = leaky(acc[0] * sc); o0.y = leaky(acc[1] * sc);
    o0.z = leaky(acc[2] * sc); o0.w = leaky(acc[3] * sc);
    o1.x = leaky(acc[4] * sc); o1.y = leaky(acc[5] * sc);
    o1.z = leaky(acc[6] * sc); o1.w = leaky(acc[7] * sc);
    float* op = out + (size_t)n * BHD + lane * 8;
    *(float4*)op = o0;
    *(float4*)(op + 4) = o1;
}

extern "C" void kernel_launch(void* const* d_in, const int* in_sizes, int n_in,
                              void* d_out, int out_size, void* d_ws, size_t ws_size,
                              hipStream_t stream)
{
    const float* feat   = (const float*)d_in[0];
    const float* W      = (const float*)d_in[1];
    const float* attn_l = (const float*)d_in[2];
    const float* attn_r = (const float*)d_in[3];
    const int*   src    = (const int*)d_in[4];
    const int*   dst    = (const int*)d_in[5];
    float* out = (float*)d_out;

    const int N = in_sizes[0] / (B * DIN);
    const int E = in_sizes[4];
    const int R = N * B;
    const int nTiles = R / 64;                    // 625 for R=40000 (R % 64 == 0)
    const int histBlocks = (E / 4 + 255) / 256;
    const int edgeBlocks = histBlocks;
    const int cvtBlocks  = (R * (DIN / 8) + 255) / 256;   // 8 floats per thread

    auto align_up = [](size_t x) { return (x + 255) & ~(size_t)255; };
    size_t off = 0;
    char* base = (char*)d_ws;
    ushort* ftb   = (ushort*)(base + off); off += align_up((size_t)R * HD * sizeof(ushort));
    ushort* featb = (ushort*)(base + off); off += align_up((size_t)R * DIN * sizeof(ushort));
    float* el   = (float*)(base + off); off += align_up((size_t)R * H * sizeof(float));
    float* er   = (float*)(base + off); off += align_up((size_t)R * H * sizeof(float));
    ushort* WT  = (ushort*)(base + off); off += align_up((size_t)NCOL * DIN * sizeof(ushort));
    int* deg    = (int*)(base + off); off += align_up((size_t)N * sizeof(int));
    int* offs   = (int*)(base + off); off += align_up((size_t)(N + 1) * sizeof(int));
    int* cursor = (int*)(base + off); off += align_up((size_t)N * sizeof(int));
    int* esrc   = (int*)(base + off); off += align_up((size_t)E * sizeof(int));
    (void)ws_size; (void)n_in; (void)out_size;

    hipMemsetAsync(deg, 0, (size_t)N * sizeof(int), stream);

    hist_prep_cvt_kernel<<<histBlocks + PREP_BLOCKS + cvtBlocks, 256, 0, stream>>>(
        dst, deg, E, W, attn_l, attn_r, WT, feat, featb, R, histBlocks);
    scan_kernel<<<1, 256, 0, stream>>>(deg, offs, cursor, N);
    proj_scatter_kernel<<<nTiles + edgeBlocks, 256, 0, stream>>>(
        featb, WT, ftb, el, er, dst, src, cursor, esrc, E, nTiles);
    agg_kernel<<<(N + 3) / 4, 256, 0, stream>>>(ftb, el, er, offs, esrc, out, N);
}

// Round 18
// 116.913 us; speedup vs baseline: 1.2727x; 1.0339x over previous
//
#include <hip/hip_runtime.h>
#include <hip/hip_bf16.h>
#include <math.h>

// BatchGATConv: N nodes, B=2 batches, DIN=128, H=4 heads, D=64, E edges.
// BEST-MEASURED CONFIGURATION (R14, 115.6us). Dispatch plan (5 dispatches):
//   D0: memset deg
//   D1: hist (int4, 4 edges/thread) || prep WT          [independent]
//   D2: scan (single small block; needs only hist)
//   D3: proj_mfma (persistent, 2 tiles/block) || scatter (needs only scan)
//   D4: agg (wave=node; width-4 depth-2 software-pipelined gather) -- at its
//       measured bandwidth floor: 147MB per-XCD cold misses @ ~3.85TB/s gather BW.

typedef unsigned short ushort;
typedef __attribute__((ext_vector_type(8))) unsigned short ushort8;
typedef __attribute__((ext_vector_type(8))) short short8v;
typedef __attribute__((ext_vector_type(4))) float f32x4;

constexpr int DIN = 128;
constexpr int B   = 2;
constexpr int H   = 4;
constexpr int D   = 64;
constexpr int HD  = H * D;      // 256
constexpr int BHD = B * HD;     // 512
constexpr int NCOL = 272;       // 256 + 16 (8 el/er cols + 8 zero pad)
constexpr int PREP_ELEMS  = NCOL * DIN;                 // 34816
constexpr int PREP_BLOCKS = (PREP_ELEMS + 255) / 256;   // 136
constexpr int SXS = 72;         // LDS transpose row stride (ushorts)

__device__ __forceinline__ float leaky(float x) { return x >= 0.f ? x : 0.2f * x; }

__device__ __forceinline__ ushort f2bf(float f) {
    return __builtin_bit_cast(ushort, __float2bfloat16(f));
}
__device__ __forceinline__ float bf2f(ushort v) {
    return __uint_as_float(((unsigned int)v) << 16);
}

// ---------------- D1: hist || prep ----------------
__global__ __launch_bounds__(256) void hist_prep_kernel(
    const int* __restrict__ dst, int* __restrict__ deg, int E,
    const float* __restrict__ W, const float* __restrict__ attn_l,
    const float* __restrict__ attn_r, ushort* __restrict__ WT, int histBlocks)
{
    const int t = threadIdx.x;
    const int b = blockIdx.x;
    if (b < histBlocks) {
        int e4 = (b * 256 + t) * 4;
        if (e4 + 3 < E) {
            int4 dd = *(const int4*)(dst + e4);
            atomicAdd(&deg[dd.x], 1); atomicAdd(&deg[dd.y], 1);
            atomicAdd(&deg[dd.z], 1); atomicAdd(&deg[dd.w], 1);
        } else {
            for (int e = e4; e < E; ++e) atomicAdd(&deg[dst[e]], 1);
        }
        return;
    }
    int id = (b - histBlocks) * 256 + t;
    if (id >= PREP_ELEMS) return;
    int c = id >> 7, k = id & 127;
    float v;
    if (c < 256) {
        v = W[k * HD + c];
    } else if (c < 264) {
        int j = c - 256, h = j & 3;
        const float* av = (j < 4 ? attn_l : attn_r) + h * D;
        const float* wp = W + k * HD + h * D;
        float s = 0.f;
        for (int d = 0; d < D; ++d) s = fmaf(wp[d], av[d], s);
        v = s;
    } else {
        v = 0.f;
    }
    WT[c * DIN + k] = f2bf(v);
}

// ---------------- D2: striped coalesced single-block scan ----------------
__global__ __launch_bounds__(256) void scan_kernel(
    const int* __restrict__ deg, int* __restrict__ offs,
    int* __restrict__ cursor, int n)
{
    __shared__ int wcarry[4];
    const int t = threadIdx.x;
    const int lane = t & 63;
    const int wid = t >> 6;
    int carry = 0;
    const int nstripes = (n + 1023) >> 10;
    for (int s = 0; s < nstripes; ++s) {
        const int base = (s << 10) + t * 4;
        int4 d = make_int4(0, 0, 0, 0);
        if (base + 3 < n) {
            d = *(const int4*)(deg + base);
        } else {
            if (base     < n) d.x = deg[base];
            if (base + 1 < n) d.y = deg[base + 1];
            if (base + 2 < n) d.z = deg[base + 2];
        }
        const int sum4 = (d.x + d.y) + (d.z + d.w);
        int inc = sum4;
#pragma unroll
        for (int o = 1; o < 64; o <<= 1) {
            int v = __shfl_up(inc, o, 64);
            if (lane >= o) inc += v;
        }
        if (lane == 63) wcarry[wid] = inc;
        __syncthreads();
        int wpre = carry;
#pragma unroll
        for (int k = 0; k < 4; ++k) if (k < wid) wpre += wcarry[k];
        const int e0 = wpre + inc - sum4;
        int4 ov;
        ov.x = e0; ov.y = e0 + d.x; ov.z = ov.y + d.y; ov.w = ov.z + d.z;
        if (base + 3 < n) {
            *(int4*)(offs + base) = ov;
            *(int4*)(cursor + base) = ov;
        } else {
            if (base     < n) { offs[base]     = ov.x; cursor[base]     = ov.x; }
            if (base + 1 < n) { offs[base + 1] = ov.y; cursor[base + 1] = ov.y; }
            if (base + 2 < n) { offs[base + 2] = ov.z; cursor[base + 2] = ov.z; }
        }
        carry += (wcarry[0] + wcarry[1]) + (wcarry[2] + wcarry[3]);
        __syncthreads();
    }
    if (t == 0) offs[n] = carry;
}

// ---------------- D3: proj_mfma (persistent) || scatter ----------------
__global__ __launch_bounds__(256) void proj_scatter_kernel(
    const float* __restrict__ feat, const ushort* __restrict__ WT,
    ushort* __restrict__ ftb, float* __restrict__ el, float* __restrict__ er,
    const int* __restrict__ dst, const int* __restrict__ src,
    int* __restrict__ cursor, int* __restrict__ esrc, int E,
    int nTiles, int PB)
{
    if ((int)blockIdx.x >= PB) {
        // ---- scatter part ----
        int e4 = (((int)blockIdx.x - PB) * 256 + (int)threadIdx.x) * 4;
        if (e4 + 3 < E) {
            int4 dd = *(const int4*)(dst + e4);
            int4 ss = *(const int4*)(src + e4);
            int p0 = atomicAdd(&cursor[dd.x], 1); esrc[p0] = ss.x;
            int p1 = atomicAdd(&cursor[dd.y], 1); esrc[p1] = ss.y;
            int p2 = atomicAdd(&cursor[dd.z], 1); esrc[p2] = ss.z;
            int p3 = atomicAdd(&cursor[dd.w], 1); esrc[p3] = ss.w;
        } else {
            for (int e = e4; e < E; ++e) {
                int pos = atomicAdd(&cursor[dst[e]], 1);
                esrc[pos] = src[e];
            }
        }
        return;
    }

    // ---- proj part (persistent over tiles) ----
    __shared__ ushort sxp[4][2][16][SXS];
    const int t = threadIdx.x;
    const int w = t >> 6;
    const int lane = t & 63;
    const int lr = lane & 15;
    const int lk = lane >> 4;

    short8v bfrag[4][4];
#pragma unroll
    for (int ct = 0; ct < 4; ++ct) {
        const int col = w * 64 + ct * 16 + lr;
#pragma unroll
        for (int ks = 0; ks < 4; ++ks)
            bfrag[ct][ks] = *(const short8v*)&WT[col * DIN + ks * 32 + lk * 8];
    }
    short8v efrag[4];
#pragma unroll
    for (int ks = 0; ks < 4; ++ks)
        efrag[ks] = *(const short8v*)&WT[(256 + lr) * DIN + ks * 32 + lk * 8];

    const int rrow = lane >> 2;
    const int seg  = lane & 3;

    for (int tile = blockIdx.x; tile < nTiles; tile += PB) {
        const int row0 = tile * 64;

        auto loadA = [&](int rt, short8v aout[4]) {
            const float* fp = feat + (size_t)(row0 + rt * 16 + lr) * DIN + lk * 8;
#pragma unroll
            for (int ks = 0; ks < 4; ++ks) {
                f32x4 x0 = *(const f32x4*)(fp + ks * 32);
                f32x4 x1 = *(const f32x4*)(fp + ks * 32 + 4);
                short8v v;
                v[0] = (short)f2bf(x0[0]); v[1] = (short)f2bf(x0[1]);
                v[2] = (short)f2bf(x0[2]); v[3] = (short)f2bf(x0[3]);
                v[4] = (short)f2bf(x1[0]); v[5] = (short)f2bf(x1[1]);
                v[6] = (short)f2bf(x1[2]); v[7] = (short)f2bf(x1[3]);
                aout[ks] = v;
            }
        };

        short8v aP[4], aN[4];
        loadA(0, aP);

#pragma unroll
        for (int rt = 0; rt < 4; ++rt) {
            if (rt < 3) loadA(rt + 1, aN);

            f32x4 acc[4] = {{0.f,0.f,0.f,0.f},{0.f,0.f,0.f,0.f},{0.f,0.f,0.f,0.f},{0.f,0.f,0.f,0.f}};
#pragma unroll
            for (int ct = 0; ct < 4; ++ct)
#pragma unroll
                for (int ks = 0; ks < 4; ++ks)
                    acc[ct] = __builtin_amdgcn_mfma_f32_16x16x32_bf16(aP[ks], bfrag[ct][ks], acc[ct], 0, 0, 0);

            ushort (* __restrict__ sw)[SXS] = sxp[w][rt & 1];
#pragma unroll
            for (int ct = 0; ct < 4; ++ct)
#pragma unroll
                for (int r = 0; r < 4; ++r)
                    sw[lk * 4 + r][ct * 16 + lr] = f2bf(acc[ct][r]);
            __builtin_amdgcn_wave_barrier();
            ushort8 o0 = *(const ushort8*)&sw[rrow][seg * 16];
            ushort8 o1 = *(const ushort8*)&sw[rrow][seg * 16 + 8];
            ushort* gp = ftb + (size_t)(row0 + rt * 16 + rrow) * HD + w * 64 + seg * 16;
            *(ushort8*)gp = o0;
            *(ushort8*)(gp + 8) = o1;

            if (rt == w) {  // extra tile: el/er columns (wave-uniform branch)
                f32x4 acce = {0.f, 0.f, 0.f, 0.f};
#pragma unroll
                for (int ks = 0; ks < 4; ++ks)
                    acce = __builtin_amdgcn_mfma_f32_16x16x32_bf16(aP[ks], efrag[ks], acce, 0, 0, 0);
#pragma unroll
                for (int r = 0; r < 4; ++r) {
                    const int row = row0 + rt * 16 + lk * 4 + r;
                    if (lr < 4)       el[row * 4 + lr]       = acce[r];
                    else if (lr < 8)  er[row * 4 + (lr - 4)] = acce[r];
                }
            }

#pragma unroll
            for (int ks = 0; ks < 4; ++ks) aP[ks] = aN[ks];
        }
    }
}

// ---------------- D4: agg (software-pipelined gather) ----------------
// One wave per dst node; lane covers cols 8*lane..8*lane+7 (ushort8 = 16B gather).
// Width-4 depth-2 pipeline: next stage's esrc/ftv/el loads issue before current
// stage's exp+FMA work, hiding the dependent gather latency chain.
__global__ __launch_bounds__(256) void agg_kernel(
    const ushort* __restrict__ ftb, const float* __restrict__ el,
    const float* __restrict__ er, const int* __restrict__ offs,
    const int* __restrict__ esrc, float* __restrict__ out, int N)
{
    const int t = threadIdx.x;
    const int n = blockIdx.x * 4 + (t >> 6);
    if (n >= N) return;
    const int lane = t & 63;
    const int bh = lane >> 3;
    const int beg = offs[n];
    const int end = offs[n + 1];

    const float erd = er[n * 8 + bh];
    const ushort8* __restrict__ ftv = (const ushort8*)ftb;

    float acc[8];
#pragma unroll
    for (int j = 0; j < 8; ++j) acc[j] = 0.f;
    float dsum = 0.f;

    int i = beg;
    if (end - beg >= 8) {
        int sA[4]; ushort8 vA[4]; float xA[4];
#pragma unroll
        for (int u = 0; u < 4; ++u) sA[u] = esrc[i + u];
#pragma unroll
        for (int u = 0; u < 4; ++u) vA[u] = ftv[(unsigned)sA[u] * 64 + lane];
#pragma unroll
        for (int u = 0; u < 4; ++u) xA[u] = el[sA[u] * 8 + bh];

        for (; i + 7 < end; i += 4) {
            int sB[4]; ushort8 vB[4]; float xB[4];
#pragma unroll
            for (int u = 0; u < 4; ++u) sB[u] = esrc[i + 4 + u];
#pragma unroll
            for (int u = 0; u < 4; ++u) vB[u] = ftv[(unsigned)sB[u] * 64 + lane];
#pragma unroll
            for (int u = 0; u < 4; ++u) xB[u] = el[sB[u] * 8 + bh];

            float w[4];
#pragma unroll
            for (int u = 0; u < 4; ++u) { w[u] = __expf(leaky(xA[u] + erd)); }
            dsum += (w[0] + w[1]) + (w[2] + w[3]);
#pragma unroll
            for (int j = 0; j < 8; ++j) {
                float a = acc[j];
#pragma unroll
                for (int u = 0; u < 4; ++u) a = fmaf(w[u], bf2f(vA[u][j]), a);
                acc[j] = a;
            }
#pragma unroll
            for (int u = 0; u < 4; ++u) { sA[u] = sB[u]; vA[u] = vB[u]; xA[u] = xB[u]; }
        }
        float w[4];
#pragma unroll
        for (int u = 0; u < 4; ++u) { w[u] = __expf(leaky(xA[u] + erd)); }
        dsum += (w[0] + w[1]) + (w[2] + w[3]);
#pragma unroll
        for (int j = 0; j < 8; ++j) {
            float a = acc[j];
#pragma unroll
            for (int u = 0; u < 4; ++u) a = fmaf(w[u], bf2f(vA[u][j]), a);
            acc[j] = a;
        }
        i += 4;
    }
    // scalar tail (<= 7 edges)
    for (; i < end; ++i) {
        int s0 = esrc[i];
        ushort8 v0 = ftv[(unsigned)s0 * 64 + lane];
        float w0 = __expf(leaky(el[s0 * 8 + bh] + erd));
        dsum += w0;
#pragma unroll
        for (int j = 0; j < 8; ++j) acc[j] = fmaf(w0, bf2f(v0[j]), acc[j]);
    }

    const float sc = (end > beg) ? (1.f / dsum) : 0.f;
    float4 o0, o1;
    o0.x = leaky(acc[0] * sc); o0.y = leaky(acc[1] * sc);
    o0.z = leaky(acc[2] * sc); o0.w = leaky(acc[3] * sc);
    o1.x = leaky(acc[4] * sc); o1.y = leaky(acc[5] * sc);
    o1.z = leaky(acc[6] * sc); o1.w = leaky(acc[7] * sc);
    float* op = out + (size_t)n * BHD + lane * 8;
    *(float4*)op = o0;
    *(float4*)(op + 4) = o1;
}

extern "C" void kernel_launch(void* const* d_in, const int* in_sizes, int n_in,
                              void* d_out, int out_size, void* d_ws, size_t ws_size,
                              hipStream_t stream)
{
    const float* feat   = (const float*)d_in[0];
    const float* W      = (const float*)d_in[1];
    const float* attn_l = (const float*)d_in[2];
    const float* attn_r = (const float*)d_in[3];
    const int*   src    = (const int*)d_in[4];
    const int*   dst    = (const int*)d_in[5];
    float* out = (float*)d_out;

    const int N = in_sizes[0] / (B * DIN);
    const int E = in_sizes[4];
    const int R = N * B;
    const int nTiles = R / 64;                    // 625 for R=40000 (R % 64 == 0)
    const int projBlocks = (nTiles + 1) / 2;      // persistent: 2 tiles per block
    const int histBlocks = (E / 4 + 255) / 256;
    const int edgeBlocks = histBlocks;

    auto align_up = [](size_t x) { return (x + 255) & ~(size_t)255; };
    size_t off = 0;
    char* base = (char*)d_ws;
    ushort* ftb = (ushort*)(base + off); off += align_up((size_t)R * HD * sizeof(ushort));
    float* el   = (float*)(base + off); off += align_up((size_t)R * H * sizeof(float));
    float* er   = (float*)(base + off); off += align_up((size_t)R * H * sizeof(float));
    ushort* WT  = (ushort*)(base + off); off += align_up((size_t)NCOL * DIN * sizeof(ushort));
    int* deg    = (int*)(base + off); off += align_up((size_t)N * sizeof(int));
    int* offs   = (int*)(base + off); off += align_up((size_t)(N + 1) * sizeof(int));
    int* cursor = (int*)(base + off); off += align_up((size_t)N * sizeof(int));
    int* esrc   = (int*)(base + off); off += align_up((size_t)E * sizeof(int));
    (void)ws_size; (void)n_in; (void)out_size;

    hipMemsetAsync(deg, 0, (size_t)N * sizeof(int), stream);

    hist_prep_kernel<<<histBlocks + PREP_BLOCKS, 256, 0, stream>>>(
        dst, deg, E, W, attn_l, attn_r, WT, histBlocks);
    scan_kernel<<<1, 256, 0, stream>>>(deg, offs, cursor, N);
    proj_scatter_kernel<<<projBlocks + edgeBlocks, 256, 0, stream>>>(
        feat, WT, ftb, el, er, dst, src, cursor, esrc, E, nTiles, projBlocks);
    agg_kernel<<<(N + 3) / 4, 256, 0, stream>>>(ftb, el, er, offs, esrc, out, N);
}